// Round 8
// baseline (488.653 us; speedup 1.0000x reference)
//
#include <hip/hip_runtime.h>
#include <hip/hip_bf16.h>

typedef __attribute__((ext_vector_type(8))) short short8;
typedef __attribute__((ext_vector_type(4))) float f32x4;

// pack 8 fp32 -> 8 bf16 (RNE) as one short8 (4 VGPRs)
__device__ __forceinline__ short8 pack8(const f32x4& a, const f32x4& b) {
    union { __hip_bfloat162 h[4]; short8 s; } u;
    u.h[0] = __float22bfloat162_rn(make_float2(a[0], a[1]));
    u.h[1] = __float22bfloat162_rn(make_float2(a[2], a[3]));
    u.h[2] = __float22bfloat162_rn(make_float2(b[0], b[1]));
    u.h[3] = __float22bfloat162_rn(make_float2(b[2], b[3]));
    return u.s;
}

// Granule swizzle (involution, store AND load) — r2..r6-proven conflict-free.
__device__ __forceinline__ int swz4(int g) { return g ^ (((g >> 4) & 3) << 1); }

// ---- 2-blocks/CU variant: 256 thr, 4 waves (2Mx2N), tile 256x128xBK32 ----
// Grid: 8192 = 512 km x 4 mt x 4 ntq. LDS 48KB/block (A 16K | B 8K, dbuf)
// -> 2 independent blocks co-resident per CU = two unsynchronized barrier
// domains; pipes (MFMA / LDS / L2-delivery / VALU-cvt) overlap ACROSS blocks
// instead of summing within one lockstep block (r4/r6 lesson).
// Per K-tile kt (16 total): issue 12 loads (tile kt+1) -> 12 ds_read + 32
// MFMA (tile kt) -> vmcnt(0) -> cvt + 6 ds_write -> lgkm -> barrier.
// Race audit: writes target buf[(kt+1)&1], read as tile kt-1; all waves
// drained those reads (lgkmcnt(0)) before kt-1's barrier. vmcnt(0) waits
// loads issued before KK (~>1200 cyc earlier) -> latency covered.
#define BUF 24576

#define ISSUE_B(KT1)                                                          \
  do {                                                                        \
    const float* q_ = Bs + (KT1) * 32;                                        \
    sB[0] = *(const f32x4*)q_;           sB[1] = *(const f32x4*)(q_ + 4);     \
    sB[2] = *(const f32x4*)(q_ + 32768); sB[3] = *(const f32x4*)(q_ + 32772); \
  } while (0)

#define ISSUE_A(KT1)                                                          \
  do {                                                                        \
    const float* q_ = As + (KT1) * 32;                                        \
    sA[0] = *(const f32x4*)q_;           sA[1] = *(const f32x4*)(q_ + 4);     \
    sA[2] = *(const f32x4*)(q_ + 32768); sA[3] = *(const f32x4*)(q_ + 32772); \
    sA[4] = *(const f32x4*)(q_ + 65536); sA[5] = *(const f32x4*)(q_ + 65540); \
    sA[6] = *(const f32x4*)(q_ + 98304); sA[7] = *(const f32x4*)(q_ + 98308); \
  } while (0)

#define KK(RB)                                                                \
  do {                                                                        \
    _Pragma("unroll") for (int mi = 0; mi < 8; ++mi)                          \
        av[mi] = *(const short8*)((RB) + ((wm * 8 + mi) << 10) + rdo);        \
    _Pragma("unroll") for (int pp = 0; pp < 4; ++pp)                          \
        bv[pp] = *(const short8*)((RB) + 16384 +                              \
                                  ((wn * 4 + pp) << 10) + rdo);               \
    __builtin_amdgcn_s_setprio(1);                                            \
    _Pragma("unroll") for (int mi = 0; mi < 8; ++mi)                          \
        _Pragma("unroll") for (int pp = 0; pp < 4; ++pp)                      \
            acc[mi][pp] = __builtin_amdgcn_mfma_f32_16x16x32_bf16(            \
                av[mi], bv[pp], acc[mi][pp], 0, 0, 0);                        \
    __builtin_amdgcn_s_setprio(0);                                            \
  } while (0)

#define WRITE_ALL(WB)                                                         \
  do {                                                                        \
    char* db_ = (WB) + 16384 + wfrag;                                         \
    *(short8*)db_ = pack8(sB[0], sB[1]);                                      \
    *(short8*)(db_ + 4096) = pack8(sB[2], sB[3]);                             \
    char* da_ = (WB) + wfrag;                                                 \
    *(short8*)da_ = pack8(sA[0], sA[1]);                                      \
    *(short8*)(da_ + 4096) = pack8(sA[2], sA[3]);                             \
    *(short8*)(da_ + 8192) = pack8(sA[4], sA[5]);                             \
    *(short8*)(da_ + 12288) = pack8(sA[6], sA[7]);                            \
  } while (0)

__global__ __launch_bounds__(256, 2)
void ens_mlp_kernel(const float* __restrict__ X,
                    const float* __restrict__ W1,
                    const float* __restrict__ B1,
                    const float* __restrict__ W2,
                    const float* __restrict__ B2,
                    float* __restrict__ out)
{
    extern __shared__ char smem[];
    const int t    = threadIdx.x;
    const int lane = t & 63;
    const int wv   = t >> 6;      // 0..3
    const int wm   = wv >> 1;     // 0..1
    const int wn   = wv & 1;      // 0..1

    // XCD-aware decode: 16 blocks of the same km adjacent on one XCD.
    const int bb  = blockIdx.x;
    const int xcd = bb & 7;
    const int j   = bb >> 3;
    const int km  = xcd * 64 + (j >> 4);   // 0..511
    const int sub = j & 15;
    const int mt  = sub >> 2;              // 0..3 (256-row batch tile)
    const int ntq = sub & 3;               // 0..3 (128-col n quarter)

    const float* __restrict__ W1k = W1 + (size_t)km * (512 * 512);

    // staging identity: lr = t>>2 (0..63), c = t&3 (k-oct).
    // A rows {lr, lr+64, lr+128, lr+192}; B rows {lr, lr+64}.
    const int lr = t >> 2;
    const int c  = t & 3;
    const float* As = X   + (size_t)(mt * 256 + lr) * 512 + c * 8;
    const float* Bs = W1k + (size_t)(ntq * 128 + lr) * 512 + c * 8;
    const int wfrag = ((lr >> 4) << 10) + (swz4((c << 4) | (lr & 15)) << 4);
    const int rdo   = swz4(lane) << 4;

    f32x4 sB[4], sA[8];

    // ---- prologue: stage tile 0 (counted drains) ----
    {
        ISSUE_B(0);
        ISSUE_A(0);
        asm volatile("s_waitcnt vmcnt(8)" ::: "memory");
        { char* d = smem + 16384 + wfrag;
          *(short8*)d = pack8(sB[0], sB[1]);
          *(short8*)(d + 4096) = pack8(sB[2], sB[3]); }
        asm volatile("s_waitcnt vmcnt(4)" ::: "memory");
        { char* d = smem + wfrag;
          *(short8*)d = pack8(sA[0], sA[1]);
          *(short8*)(d + 4096) = pack8(sA[2], sA[3]); }
        asm volatile("s_waitcnt vmcnt(0)" ::: "memory");
        { char* d = smem + wfrag;
          *(short8*)(d + 8192)  = pack8(sA[4], sA[5]);
          *(short8*)(d + 12288) = pack8(sA[6], sA[7]); }
        asm volatile("s_waitcnt lgkmcnt(0)" ::: "memory");
        __builtin_amdgcn_sched_barrier(0);
        __builtin_amdgcn_s_barrier();
    }

    f32x4 acc[8][4];
#pragma unroll
    for (int i = 0; i < 8; ++i)
#pragma unroll
        for (int p = 0; p < 4; ++p)
            acc[i][p] = (f32x4)0.0f;

    short8 av[8], bv[4];

#pragma unroll 1
    for (int kt = 0; kt < 15; ++kt) {
        const char* rb = smem + (kt & 1) * BUF;
        char* wb       = smem + ((kt + 1) & 1) * BUF;

        ISSUE_B(kt + 1);
        ISSUE_A(kt + 1);
        __builtin_amdgcn_sched_barrier(0);   // loads issue before ds_reads
        KK(rb);                              // 12 ds_read + 32 MFMA
        asm volatile("s_waitcnt vmcnt(0)" ::: "memory");
        WRITE_ALL(wb);
        asm volatile("s_waitcnt lgkmcnt(0)" ::: "memory");
        __builtin_amdgcn_sched_barrier(0);
        __builtin_amdgcn_s_barrier();
    }
    {   // kt = 15: compute only
        const char* rb = smem + BUF;
        KK(rb);
    }

    // ---- fused epilogue: partial over this block's 128 n-cols ----
    const int nc = lane & 15;
    const int kq = lane >> 4;
    float b1v[4], w2v[4];
#pragma unroll
    for (int pp = 0; pp < 4; ++pp) {
        int n = ntq * 128 + (wn * 4 + pp) * 16 + nc;
        b1v[pp] = B1[km * 512 + n];
        w2v[pp] = W2[km * 512 + n];
    }

    float* lout = (float*)smem;   // buf0 region; tile15 read buf1 -> no clash
#pragma unroll
    for (int i = 0; i < 8; ++i) {
#pragma unroll
        for (int r = 0; r < 4; ++r) {
            float s = 0.f;
#pragma unroll
            for (int pp = 0; pp < 4; ++pp) {
                float h = acc[i][pp][r] + b1v[pp];
                h = h > 0.f ? h : 0.f;
                s += h * w2v[pp];
            }
#pragma unroll
            for (int d = 1; d < 16; d <<= 1)
                s += __shfl_xor(s, d, 64);
            if (nc == 0) {
                int row = wm * 128 + i * 16 + kq * 4 + r;
                lout[row * 2 + wn] = s;
            }
        }
    }
    __syncthreads();
    {
        float s = lout[t * 2 + 0] + lout[t * 2 + 1];
        if (ntq == 0) s += B2[km];
        int b = mt * 256 + t;
        // out[b, e, o] with k = o*E + e  ->  flat b*512 + (km%8)*64 + (km/8)
        atomicAdd(out + (size_t)b * 512 + (km & 7) * 64 + (km >> 3), s);
    }
}

extern "C" void kernel_launch(void* const* d_in, const int* in_sizes, int n_in,
                              void* d_out, int out_size, void* d_ws, size_t ws_size,
                              hipStream_t stream) {
    const float* X  = (const float*)d_in[0];
    const float* W1 = (const float*)d_in[1];
    const float* B1 = (const float*)d_in[2];
    const float* W2 = (const float*)d_in[3];
    const float* B2 = (const float*)d_in[4];
    float* out = (float*)d_out;

    hipMemsetAsync(out, 0, (size_t)out_size * sizeof(float), stream);
    ens_mlp_kernel<<<dim3(8192), dim3(256), 2 * BUF, stream>>>(X, W1, B1, W2, B2, out);
}

// Round 9
// 470.155 us; speedup vs baseline: 1.0393x; 1.0393x over previous
//
#include <hip/hip_runtime.h>
#include <hip/hip_bf16.h>

typedef __attribute__((ext_vector_type(8))) short short8;
typedef __attribute__((ext_vector_type(4))) float f32x4;

// pack 8 fp32 -> 8 bf16 (RNE) as one short8 (4 VGPRs)
__device__ __forceinline__ short8 pack8(const f32x4& a, const f32x4& b) {
    union { __hip_bfloat162 h[4]; short8 s; } u;
    u.h[0] = __float22bfloat162_rn(make_float2(a[0], a[1]));
    u.h[1] = __float22bfloat162_rn(make_float2(a[2], a[3]));
    u.h[2] = __float22bfloat162_rn(make_float2(b[0], b[1]));
    u.h[3] = __float22bfloat162_rn(make_float2(b[2], b[3]));
    return u.s;
}

// r2..r7-proven involution swizzle (fallback kernel only)
__device__ __forceinline__ int swz4(int g) { return g ^ (((g >> 4) & 3) << 1); }

// async global->LDS DMA, 16B per lane; LDS dest = wave-uniform base + lane*16
#define GLDS(GP, LP)                                                          \
    __builtin_amdgcn_global_load_lds(                                         \
        (__attribute__((address_space(1))) void*)(void*)(GP),                 \
        (__attribute__((address_space(3))) void*)(void*)(LP), 16, 0, 0)

// ============================================================================
// Kernel 1: fp32 -> bf16 conversion + MFMA-granule relayout into d_ws.
// Granule (idx, ks) = 1KB: lane l holds row idx*16+(l&15), k ks*32+(l>>4)*8..+8.
// W1b: [km][f 0..31][ks 0..15] granules; Xb (at +134217728 shorts): [mf 0..63][ks].
// One wave per (km,f) / per mf; writes coalesced 16B/lane; reads served via L2
// line reuse across the 16-ks loop (32KB working set per wave).
// ============================================================================
__global__ __launch_bounds__(256)
void ens_cvt(const float* __restrict__ X, const float* __restrict__ W1,
             short* __restrict__ WS)
{
    const int t = threadIdx.x, lane = t & 63, wv = t >> 6;
    const int g = blockIdx.x * 4 + wv;
    const int row16 = lane & 15, koct = lane >> 4;
    const float* src;
    short* dst;
    if (blockIdx.x < 4096) {                       // W1: g = km*32 + f
        const int km = g >> 5, f = g & 31;
        src = W1 + (size_t)km * 262144 + (size_t)(f * 16 + row16) * 512 + koct * 8;
        dst = WS + (size_t)km * 262144 + (size_t)(f * 16) * 512 + lane * 8;
    } else {                                       // X: mf = g - 16384 (0..63)
        const int mf = g - 16384;
        src = X + (size_t)(mf * 16 + row16) * 512 + koct * 8;
        dst = WS + 134217728ull + (size_t)(mf * 16) * 512 + lane * 8;
    }
#pragma unroll
    for (int ks = 0; ks < 16; ++ks) {
        f32x4 a = *(const f32x4*)(src + ks * 32);
        f32x4 b = *(const f32x4*)(src + ks * 32 + 4);
        *(short8*)(dst + ks * 512) = pack8(a, b);
    }
}

// ============================================================================
// Kernel 2: bf16 GEMM, m97/m201-style: global_load_lds DMA staging, 4-slot
// LDS ring (K=32 halves), prefetch depth 3, counted vmcnt(8) (T4), setprio(T5).
// Grid 4096 = 512 km x 4 mt x 2 nt; 512 thr = 8 waves (2Mx4N); wave 128x64.
// LDS = 4 slots x (A 16KB | B 16KB) = 128KB. No cvt, no ds_write, no swizzle:
// granules pre-permuted in ws, DMA dest linear, ds_read_b128 at lane*16.
// Ring audit: ISSUE(h+3) targets slot (h-1)&3, whose reads (half h-1) were
// consumed by MFMAs before iter h-1's barrier. vmcnt(8) at end of iter h
// leaves batches h+2,h+3 (4 instr each) in flight; oldest (h+1) done -> safe
// to read after barrier. Tail: h=13 -> vmcnt(4), h=14 -> vmcnt(0).
// ============================================================================
#define ISSUE(H)                                                              \
  do {                                                                        \
    char* sb_ = smem + ((H) & 3) * 32768;                                     \
    GLDS(g0 + (H) * 512, sb_ + (size_t)(s0 + 0) * 1024);                      \
    GLDS(g1 + (H) * 512, sb_ + (size_t)(s0 + 1) * 1024);                      \
    GLDS(g2 + (H) * 512, sb_ + (size_t)(s0 + 2) * 1024);                      \
    GLDS(g3 + (H) * 512, sb_ + (size_t)(s0 + 3) * 1024);                      \
  } while (0)

#define KK(H)                                                                 \
  do {                                                                        \
    const char* rb_ = smem + ((H) & 3) * 32768;                               \
    _Pragma("unroll") for (int mi = 0; mi < 8; ++mi)                          \
        av[mi] = *(const short8*)(rb_ + (wm * 8 + mi) * 1024 + (lane << 4));  \
    _Pragma("unroll") for (int pp = 0; pp < 4; ++pp)                          \
        bv[pp] = *(const short8*)(rb_ + 16384 +                               \
                                  (wn * 4 + pp) * 1024 + (lane << 4));        \
    __builtin_amdgcn_s_setprio(1);                                            \
    _Pragma("unroll") for (int mi = 0; mi < 8; ++mi)                          \
        _Pragma("unroll") for (int pp = 0; pp < 4; ++pp)                      \
            acc[mi][pp] = __builtin_amdgcn_mfma_f32_16x16x32_bf16(            \
                av[mi], bv[pp], acc[mi][pp], 0, 0, 0);                        \
    __builtin_amdgcn_s_setprio(0);                                            \
  } while (0)

__global__ __launch_bounds__(512, 2)
void ens_gemm_dma(const short* __restrict__ Xb, const short* __restrict__ W1b,
                  const float* __restrict__ B1, const float* __restrict__ W2,
                  const float* __restrict__ B2, float* __restrict__ out)
{
    extern __shared__ char smem[];
    const int t    = threadIdx.x;
    const int lane = t & 63;
    const int wv   = t >> 6;
    const int wm   = wv >> 2;     // 0..1
    const int wn   = wv & 3;      // 0..3

    // XCD-aware decode: 8 blocks of the same km adjacent on one XCD.
    const int bb  = blockIdx.x;
    const int xcd = bb & 7;
    const int j   = bb >> 3;
    const int km  = xcd * 64 + (j >> 3);   // 0..511
    const int sub = j & 7;
    const int mt  = sub >> 1;              // 0..3 (256-row batch tile)
    const int nt  = sub & 1;               // 0..1 (256-col n half)

    // DMA work split: wave wv owns granule slots s0..s0+3 (s<16: A, else B).
    // Waves 0-3 stage A (uniform), waves 4-7 stage B (uniform).
    const int s0 = wv * 4;
    const short* g0;
    const short* g1;
    const short* g2;
    const short* g3;
    {
        auto gsrc = [&](int s) -> const short* {
            if (s < 16)
                return Xb + (size_t)(mt * 16 + s) * 16 * 512 + lane * 8;
            return W1b + (size_t)km * 262144 +
                   (size_t)(nt * 16 + (s - 16)) * 16 * 512 + lane * 8;
        };
        g0 = gsrc(s0); g1 = gsrc(s0 + 1); g2 = gsrc(s0 + 2); g3 = gsrc(s0 + 3);
    }

    f32x4 acc[8][4];
#pragma unroll
    for (int i = 0; i < 8; ++i)
#pragma unroll
        for (int p = 0; p < 4; ++p)
            acc[i][p] = (f32x4)0.0f;

    short8 av[8], bv[4];

    // prologue: fill 3 slots, wait slot 0 complete (8 = two 4-load batches out)
    ISSUE(0);
    ISSUE(1);
    ISSUE(2);
    asm volatile("s_waitcnt vmcnt(8)" ::: "memory");
    __builtin_amdgcn_sched_barrier(0);
    __builtin_amdgcn_s_barrier();
    __builtin_amdgcn_sched_barrier(0);

#pragma unroll 1
    for (int h = 0; h < 16; ++h) {
        if (h < 13) ISSUE(h + 3);
        KK(h);
        if (h < 13)       asm volatile("s_waitcnt vmcnt(8)" ::: "memory");
        else if (h == 13) asm volatile("s_waitcnt vmcnt(4)" ::: "memory");
        else if (h == 14) asm volatile("s_waitcnt vmcnt(0)" ::: "memory");
        if (h < 15) {
            __builtin_amdgcn_sched_barrier(0);
            __builtin_amdgcn_s_barrier();
            __builtin_amdgcn_sched_barrier(0);
        }
    }

    // ---- fused epilogue (r6-proven): relu + dot(W2) partials + scatter ----
    const int nc = lane & 15;
    const int kq = lane >> 4;
    float b1v[4], w2v[4];
#pragma unroll
    for (int pp = 0; pp < 4; ++pp) {
        int n = nt * 256 + (wn * 4 + pp) * 16 + nc;
        b1v[pp] = B1[km * 512 + n];
        w2v[pp] = W2[km * 512 + n];
    }

    float* lout = (float*)smem;   // slot0 region; last read was half 12 -> safe
#pragma unroll
    for (int i = 0; i < 8; ++i) {
#pragma unroll
        for (int r = 0; r < 4; ++r) {
            float s = 0.f;
#pragma unroll
            for (int pp = 0; pp < 4; ++pp) {
                float h = acc[i][pp][r] + b1v[pp];
                h = h > 0.f ? h : 0.f;
                s += h * w2v[pp];
            }
#pragma unroll
            for (int d = 1; d < 16; d <<= 1)
                s += __shfl_xor(s, d, 64);
            if (nc == 0) {
                int row = wm * 128 + i * 16 + kq * 4 + r;
                lout[row * 4 + wn] = s;
            }
        }
    }
    __syncthreads();
    if (t < 256) {
        float s = lout[t * 4 + 0] + lout[t * 4 + 1] + lout[t * 4 + 2] + lout[t * 4 + 3];
        if (nt == 0) s += B2[km];
        int b = mt * 256 + t;
        // out[b, e, o] with k = o*E + e  ->  flat b*512 + (km%8)*64 + (km/8)
        atomicAdd(out + (size_t)b * 512 + (km & 7) * 64 + (km >> 3), s);
    }
}

// ============================================================================
// Fallback (r6 verbatim, 428 µs): used when ws_size < 269,484,032 bytes.
// ============================================================================
#define FISSUE(S, BASE, KT1)                                                  \
  do {                                                                        \
    const float* q_ = (BASE) + (KT1) * 64;                                    \
    S[0] = *(const f32x4*)q_;          S[1] = *(const f32x4*)(q_ + 4);        \
    S[2] = *(const f32x4*)(q_ + 32);   S[3] = *(const f32x4*)(q_ + 36);       \
    const float* q2_ = q_ + 65536;                                            \
    S[4] = *(const f32x4*)q2_;         S[5] = *(const f32x4*)(q2_ + 4);       \
    S[6] = *(const f32x4*)(q2_ + 32);  S[7] = *(const f32x4*)(q2_ + 36);      \
  } while (0)

#define FWRITEB(S, WB, OPOFF)                                                 \
  do {                                                                        \
    char* d0_ = (WB) + (OPOFF) + wfrag;                                       \
    *(short8*)d0_ = pack8(S[0], S[1]);                                        \
    *(short8*)(d0_ + 1024) = pack8(S[2], S[3]);                               \
    char* d1_ = d0_ + 16384;                                                  \
    *(short8*)d1_ = pack8(S[4], S[5]);                                        \
    *(short8*)(d1_ + 1024) = pack8(S[6], S[7]);                               \
  } while (0)

#define FKK(RB, KKV)                                                          \
  do {                                                                        \
    _Pragma("unroll") for (int mi = 0; mi < 8; ++mi)                          \
        av[mi] = *(const short8*)((RB) +                                      \
            (((wm * 8 + mi) * 2 + (KKV)) << 10) + rdo);                       \
    _Pragma("unroll") for (int pp = 0; pp < 4; ++pp)                          \
        bv[pp] = *(const short8*)((RB) + 32768 +                              \
            (((wn * 4 + pp) * 2 + (KKV)) << 10) + rdo);                       \
    __builtin_amdgcn_s_setprio(1);                                            \
    _Pragma("unroll") for (int mi = 0; mi < 8; ++mi)                          \
        _Pragma("unroll") for (int pp = 0; pp < 4; ++pp)                      \
            acc[mi][pp] = __builtin_amdgcn_mfma_f32_16x16x32_bf16(            \
                av[mi], bv[pp], acc[mi][pp], 0, 0, 0);                        \
    __builtin_amdgcn_s_setprio(0);                                            \
  } while (0)

#define FPRO_WRITE(TT, ROFF)                                                  \
  do {                                                                        \
    short8 a_ = pack8(TT[0], TT[1]);                                          \
    short8 b_ = pack8(TT[2], TT[3]);                                          \
    char* d_ = smem + (ROFF) + wfrag;                                         \
    *(short8*)d_ = a_;                                                        \
    *(short8*)(d_ + 1024) = b_;                                               \
  } while (0)

__global__ __launch_bounds__(512, 2)
void ens_mlp_fallback(const float* __restrict__ X,
                      const float* __restrict__ W1,
                      const float* __restrict__ B1,
                      const float* __restrict__ W2,
                      const float* __restrict__ B2,
                      float* __restrict__ out)
{
    extern __shared__ char smem[];
    const int t    = threadIdx.x;
    const int lane = t & 63;
    const int wv   = t >> 6;
    const int wm   = wv >> 2;
    const int wn   = wv & 3;

    const int bb  = blockIdx.x;
    const int xcd = bb & 7;
    const int j   = bb >> 3;
    const int km  = xcd * 64 + (j >> 3);
    const int sub = j & 7;
    const int mt  = sub >> 1;
    const int nt  = sub & 1;

    const float* __restrict__ W1k = W1 + (size_t)km * (512 * 512);

    const int lr = t >> 2;
    const int c  = t & 3;
    const float* As = X   + (size_t)(mt * 256 + lr) * 512 + c * 8;
    const float* Bs = W1k + (size_t)(nt * 256 + lr) * 512 + c * 8;
    const int wfrag = ((lr >> 4) << 11) + (swz4((c << 4) | (lr & 15)) << 4);
    const int rdo   = swz4(lane) << 4;

    {
        f32x4 t0[4], t1[4], t2[4], t3[4];
        const float* q;
        q = As;          t0[0]=*(const f32x4*)q; t0[1]=*(const f32x4*)(q+4); t0[2]=*(const f32x4*)(q+32); t0[3]=*(const f32x4*)(q+36);
        q = As + 65536;  t1[0]=*(const f32x4*)q; t1[1]=*(const f32x4*)(q+4); t1[2]=*(const f32x4*)(q+32); t1[3]=*(const f32x4*)(q+36);
        q = Bs;          t2[0]=*(const f32x4*)q; t2[1]=*(const f32x4*)(q+4); t2[2]=*(const f32x4*)(q+32); t2[3]=*(const f32x4*)(q+36);
        q = Bs + 65536;  t3[0]=*(const f32x4*)q; t3[1]=*(const f32x4*)(q+4); t3[2]=*(const f32x4*)(q+32); t3[3]=*(const f32x4*)(q+36);
        asm volatile("s_waitcnt vmcnt(12)" ::: "memory"); FPRO_WRITE(t0, 0);
        asm volatile("s_waitcnt vmcnt(8)"  ::: "memory"); FPRO_WRITE(t1, 16384);
        asm volatile("s_waitcnt vmcnt(4)"  ::: "memory"); FPRO_WRITE(t2, 32768);
        asm volatile("s_waitcnt vmcnt(0)"  ::: "memory"); FPRO_WRITE(t3, 49152);
        asm volatile("s_waitcnt lgkmcnt(0)" ::: "memory");
        __builtin_amdgcn_sched_barrier(0);
        __builtin_amdgcn_s_barrier();
    }

    f32x4 acc[8][4];
#pragma unroll
    for (int i = 0; i < 8; ++i)
#pragma unroll
        for (int p = 0; p < 4; ++p)
            acc[i][p] = (f32x4)0.0f;

    short8 av[8], bv[4];
    f32x4 sS[8];

#pragma unroll 1
    for (int kt = 0; kt < 7; ++kt) {
        const char* rb = smem + (kt & 1) * 65536;
        char* wb       = smem + ((kt + 1) & 1) * 65536;

        FISSUE(sS, Bs, kt + 1);
        FKK(rb, 0);
        asm volatile("s_waitcnt vmcnt(0)" ::: "memory");
        FWRITEB(sS, wb, 32768);
        FISSUE(sS, As, kt + 1);
        FKK(rb, 1);
        asm volatile("s_waitcnt vmcnt(0)" ::: "memory");
        FWRITEB(sS, wb, 0);
        asm volatile("s_waitcnt lgkmcnt(0)" ::: "memory");
        __builtin_amdgcn_sched_barrier(0);
        __builtin_amdgcn_s_barrier();
    }
    {
        const char* rb = smem + 65536;
        FKK(rb, 0);
        FKK(rb, 1);
    }

    const int nc = lane & 15;
    const int kq = lane >> 4;
    float b1v[4], w2v[4];
#pragma unroll
    for (int pp = 0; pp < 4; ++pp) {
        int n = nt * 256 + (wn * 4 + pp) * 16 + nc;
        b1v[pp] = B1[km * 512 + n];
        w2v[pp] = W2[km * 512 + n];
    }

    float* lout = (float*)smem;
#pragma unroll
    for (int i = 0; i < 8; ++i) {
#pragma unroll
        for (int r = 0; r < 4; ++r) {
            float s = 0.f;
#pragma unroll
            for (int pp = 0; pp < 4; ++pp) {
                float h = acc[i][pp][r] + b1v[pp];
                h = h > 0.f ? h : 0.f;
                s += h * w2v[pp];
            }
#pragma unroll
            for (int d = 1; d < 16; d <<= 1)
                s += __shfl_xor(s, d, 64);
            if (nc == 0) {
                int row = wm * 128 + i * 16 + kq * 4 + r;
                lout[row * 4 + wn] = s;
            }
        }
    }
    __syncthreads();
    if (t < 256) {
        float s = lout[t * 4 + 0] + lout[t * 4 + 1] + lout[t * 4 + 2] + lout[t * 4 + 3];
        if (nt == 0) s += B2[km];
        int b = mt * 256 + t;
        atomicAdd(out + (size_t)b * 512 + (km & 7) * 64 + (km >> 3), s);
    }
}

extern "C" void kernel_launch(void* const* d_in, const int* in_sizes, int n_in,
                              void* d_out, int out_size, void* d_ws, size_t ws_size,
                              hipStream_t stream) {
    const float* X  = (const float*)d_in[0];
    const float* W1 = (const float*)d_in[1];
    const float* B1 = (const float*)d_in[2];
    const float* W2 = (const float*)d_in[3];
    const float* B2 = (const float*)d_in[4];
    float* out = (float*)d_out;

    hipMemsetAsync(out, 0, (size_t)out_size * sizeof(float), stream);

    const size_t NEED = 269484032ull;  // W1b 268MB + Xb 1MB (bf16, granule order)
    if (ws_size >= NEED) {
        short* WS = (short*)d_ws;
        ens_cvt<<<dim3(4112), dim3(256), 0, stream>>>(X, W1, WS);
        ens_gemm_dma<<<dim3(4096), dim3(512), 131072, stream>>>(
            WS + 134217728ull, WS, B1, W2, B2, out);
    } else {
        ens_mlp_fallback<<<dim3(4096), dim3(512), 131072, stream>>>(
            X, W1, B1, W2, B2, out);
    }
}